// Round 7
// baseline (2411.280 us; speedup 1.0000x reference)
//
#include <hip/hip_runtime.h>

// ============================================================================
// Compile-time replication of the reference's Wigner-3j / tensor-product
// structure (Racah formula + e3nn real<->complex change of basis).
// ============================================================================

constexpr double cfact(int n){ double r = 1.0; for (int i = 2; i <= n; ++i) r *= (double)i; return r; }

constexpr double csqrt(double x){
  if (x <= 0.0) return 0.0;
  double g = x > 1.0 ? x : 1.0;
  for (int i = 0; i < 50; ++i) g = 0.5*(g + x/g);
  return g;
}

struct CD { double re, im; };

constexpr double su2_cg(int j1,int j2,int j3,int m1,int m2){
  int m3 = m1 + m2;
  if (m3 < -j3 || m3 > j3) return 0.0;
  double p1 = (2.0*j3+1.0)*cfact(j1+j2-j3)*cfact(j1-j2+j3)*cfact(-j1+j2+j3)/cfact(j1+j2+j3+1);
  double p2 = cfact(j1+m1)*cfact(j1-m1)*cfact(j2+m2)*cfact(j2-m2)*cfact(j3+m3)*cfact(j3-m3);
  double pref = csqrt(p1*p2);
  int k0 = 0;
  if (j2-j3-m1 > k0) k0 = j2-j3-m1;
  if (j1+m2-j3 > k0) k0 = j1+m2-j3;
  int k1 = j1+j2-j3;
  if (j1-m1 < k1) k1 = j1-m1;
  if (j2+m2 < k1) k1 = j2+m2;
  double s = 0.0;
  for (int k = k0; k <= k1; ++k){
    double t = 1.0/(cfact(k)*cfact(j1+j2-j3-k)*cfact(j1-m1-k)*cfact(j2+m2-k)
                    *cfact(j3-j2+m1+k)*cfact(j3-j1-m2+k));
    s += (k & 1) ? -t : t;
  }
  return pref*s;
}

struct QRow { int n; int col[2]; CD q[2]; };
constexpr QRow qrow(int l, int r){
  QRow R{};
  constexpr double s2 = 0.70710678118654752440;
  int m = r - l;
  if (m < 0){
    R.n = 2;
    R.col[0] = l - m; R.q[0] = CD{s2, 0.0};
    R.col[1] = l + m; R.q[1] = CD{0.0, -s2};
  } else if (m == 0){
    R.n = 1; R.col[0] = l; R.q[0] = CD{1.0, 0.0};
  } else {
    double sg = (m & 1) ? -1.0 : 1.0;
    R.n = 2;
    R.col[0] = l + m; R.q[0] = CD{sg*s2, 0.0};
    R.col[1] = l - m; R.q[1] = CD{0.0, sg*s2};
  }
  int ph = l & 3;   // multiply by (-i)^l
  for (int t = 0; t < R.n; ++t){
    double a = R.q[t].re, b = R.q[t].im;
    if      (ph == 1) R.q[t] = CD{ b, -a};
    else if (ph == 2) R.q[t] = CD{-a, -b};
    else if (ph == 3) R.q[t] = CD{-b,  a};
  }
  return R;
}

constexpr int MAXNZ = 160;
struct W3NZ { int n; int ijk[MAXNZ]; float v[MAXNZ]; };

constexpr W3NZ build_w3(int l1,int l2,int l3){
  double re[7][7][7]{};
  int d1 = 2*l1+1, d2 = 2*l2+1, d3 = 2*l3+1;
  for (int i = 0; i < d1; ++i) for (int k = 0; k < d2; ++k){
    int m1 = i - l1, m2 = k - l2, m3 = m1 + m2;
    if (m3 < -l3 || m3 > l3) continue;
    int n = m3 + l3;
    double cg = su2_cg(l1,l2,l3,m1,m2);
    if (cg == 0.0) continue;
    QRow q1 = qrow(l1,i), q2 = qrow(l2,k), q3 = qrow(l3,n);
    for (int a = 0; a < q1.n; ++a) for (int b = 0; b < q2.n; ++b) for (int c = 0; c < q3.n; ++c){
      CD A = q1.q[a], B = q2.q[b], C = q3.q[c];
      C.im = -C.im;
      CD AB{A.re*B.re - A.im*B.im, A.re*B.im + A.im*B.re};
      double tre = AB.re*C.re - AB.im*C.im;
      re[q1.col[a]][q2.col[b]][q3.col[c]] += tre*cg;
    }
  }
  double nrm = 0.0;
  for (int i = 0; i < d1; ++i) for (int j = 0; j < d2; ++j) for (int k = 0; k < d3; ++k)
    nrm += re[i][j][k]*re[i][j][k];
  nrm = csqrt(nrm);
  W3NZ R{};
  for (int i = 0; i < d1; ++i) for (int j = 0; j < d2; ++j) for (int k = 0; k < d3; ++k){
    double val = re[i][j][k]/nrm;
    if (val > 1e-9 || val < -1e-9){
      R.ijk[R.n] = i | (j << 3) | (k << 6);
      R.v[R.n]   = (float)val;
      R.n++;
    }
  }
  return R;
}

struct C3 { int l1,l2,l3; };
constexpr C3 combo_at(int cid){
  int c = 0;
  for (int a = 0; a <= 3; ++a) for (int b = 0; b <= 3; ++b){
    int lmin = a > b ? a-b : b-a;
    int lmax = a+b > 3 ? 3 : a+b;
    for (int lo = lmin; lo <= lmax; ++lo){ if (c == cid) return C3{a,b,lo}; ++c; }
  }
  return C3{0,0,0};
}
constexpr int cid_of(int l1,int l2,int l3){
  int c = 0;
  for (int a = 0; a <= 3; ++a) for (int b = 0; b <= 3; ++b){
    int lmin = a > b ? a-b : b-a;
    int lmax = a+b > 3 ? 3 : a+b;
    for (int lo = lmin; lo <= lmax; ++lo){ if (a==l1 && b==l2 && lo==l3) return c; ++c; }
  }
  return -1;
}

// All 34 Wigner tables, split into two constexpr evals (constexpr-step budget)
struct W3Half { W3NZ w[17]; };
constexpr W3Half build_w3_half(int base){
  W3Half H{};
  for (int i = 0; i < 17; ++i){
    C3 c = combo_at(base + i);
    H.w[i] = build_w3(c.l1, c.l2, c.l3);
  }
  return H;
}
constexpr W3Half W3H0 = build_w3_half(0);
constexpr W3Half W3H1 = build_w3_half(17);
constexpr const W3NZ& w3_of(int cid){ return cid < 17 ? W3H0.w[cid] : W3H1.w[cid-17]; }

// ----------------------------------------------------------------------------
// Tensor-product path tables. scale folds sqrt((2lo+1)/fan) * 0.25 (neighbor
// normalization of the input node features).
// ----------------------------------------------------------------------------
struct Irr { int mul, l, p; };
constexpr Irr IRR_SH_A[4]  = {{1,0,1},{1,1,-1},{1,2,1},{1,3,-1}};
constexpr Irr IRR_MID_A[8] = {{5,0,-1},{5,0,1},{5,1,-1},{5,1,1},{5,2,-1},{5,2,1},{5,3,-1},{5,3,1}};
constexpr Irr IRR_OUT_A[1] = {{64,0,1}};

struct PathT { int o1,m1,l1,o2,l2,oo,mo,lo,ioi,wof,cid; float scale; };
struct TPD   { int np; int d1tot, d2tot, dotot, wtot; PathT p[68]; };

constexpr TPD build_tp(const Irr* I1, int n1, const Irr* I2, int n2, const Irr* IO, int no){
  TPD T{};
  int o1s[8]{}, o2s[8]{}, oos[8]{};
  { int off=0; for (int i=0;i<n1;++i){ o1s[i]=off; off += I1[i].mul*(2*I1[i].l+1); } T.d1tot=off; }
  { int off=0; for (int i=0;i<n2;++i){ o2s[i]=off; off += I2[i].mul*(2*I2[i].l+1); } T.d2tot=off; }
  { int off=0; for (int i=0;i<no;++i){ oos[i]=off; off += IO[i].mul*(2*IO[i].l+1); } T.dotot=off; }
  int wof = 0;
  for (int i1=0;i1<n1;++i1) for (int i2=0;i2<n2;++i2) for (int io=0;io<no;++io){
    int L1=I1[i1].l, L2=I2[i2].l, LO=IO[io].l;
    int dl = L1>L2 ? L1-L2 : L2-L1;
    if (IO[io].p == I1[i1].p*I2[i2].p && dl <= LO && LO <= L1+L2){
      PathT& P = T.p[T.np];
      P.o1=o1s[i1]; P.m1=I1[i1].mul; P.l1=L1;
      P.o2=o2s[i2]; P.l2=L2;
      P.oo=oos[io]; P.mo=IO[io].mul; P.lo=LO; P.ioi=io;
      P.wof=wof; P.cid=cid_of(L1,L2,LO);
      wof += I1[i1].mul * I2[i2].mul * IO[io].mul;
      T.np++;
    }
  }
  T.wtot = wof;
  for (int p = 0; p < T.np; ++p){
    int fan = 0;
    for (int q = 0; q < T.np; ++q) if (T.p[q].ioi == T.p[p].ioi) fan += T.p[q].m1;
    T.p[p].scale = (float)(csqrt((2.0*T.p[p].lo+1.0)/(double)fan) * 0.25);
  }
  return T;
}

template<int ID> struct TPSel;
template<> struct TPSel<0>{ static constexpr TPD v = build_tp(IRR_SH_A,4,  IRR_SH_A,4, IRR_MID_A,8); };
template<> struct TPSel<1>{ static constexpr TPD v = build_tp(IRR_MID_A,8, IRR_SH_A,4, IRR_MID_A,8); };
template<> struct TPSel<2>{ static constexpr TPD v = build_tp(IRR_MID_A,8, IRR_SH_A,4, IRR_OUT_A,1); };

static_assert(TPSel<0>::v.np == 34 && TPSel<0>::v.wtot == 170,  "TP_IN structure mismatch");
static_assert(TPSel<1>::v.np == 68 && TPSel<1>::v.wtot == 1700, "TP_LAYER structure mismatch");
static_assert(TPSel<2>::v.np == 4  && TPSel<2>::v.wtot == 1280, "TP_OUT structure mismatch");
static_assert(TPSel<0>::v.d1tot == 16 && TPSel<0>::v.dotot == 160, "dims");
static_assert(TPSel<1>::v.d1tot == 160 && TPSel<1>::v.dotot == 160, "dims");
static_assert(TPSel<2>::v.d1tot == 160 && TPSel<2>::v.dotot == 64, "dims");

// ----------------------------------------------------------------------------
// Step-2 tables: per output column c of nodeOut, CSR list of
// (M_idx = (o2+jj)*D1 + o1+u*d1+ii, w_idx, coef = w3v*scale):
//   out[c] = sum entries coef * w[w_idx] * M[M_idx],  M = sum_e sh_e (x) x_src
// ----------------------------------------------------------------------------
struct S2E { unsigned mw; float c; };   // mw = (m_idx<<11) | w_idx
template<int MAXE> struct S2Tab { int ptr[161]; S2E e[MAXE]; };

template<int TPID, int MAXE>
constexpr S2Tab<MAXE> build_s2(){
  S2Tab<MAXE> T{};
  const TPD& D = TPSel<TPID>::v;
  for (int c = 0; c <= 160; ++c) T.ptr[c] = 0;
  for (int pass = 0; pass < 2; ++pass){
    int cur[161]{};
    if (pass == 1){
      for (int c = 0; c < 160; ++c) T.ptr[c+1] += T.ptr[c];
      for (int c = 0; c < 160; ++c) cur[c] = T.ptr[c];
    }
    for (int p = 0; p < D.np; ++p){
      const PathT& P = D.p[p];
      const W3NZ& W = w3_of(P.cid);
      int d1 = 2*P.l1+1, dd = 2*P.lo+1;
      for (int u = 0; u < P.m1; ++u)
        for (int ni = 0; ni < W.n; ++ni){
          int ijk = W.ijk[ni]; int ii = ijk&7, jj = (ijk>>3)&7, kk = ijk>>6;
          for (int wj = 0; wj < P.mo; ++wj){
            int col = P.oo + wj*dd + kk;
            if (pass == 0) T.ptr[col+1]++;
            else {
              int at = cur[col]++;
              T.e[at].mw = ((unsigned)((P.o2+jj)*D.d1tot + P.o1 + u*d1 + ii) << 11)
                         | (unsigned)(P.wof + u*P.mo + wj);
              T.e[at].c  = W.v[ni]*P.scale;
            }
          }
        }
    }
  }
  return T;
}

// TP2 (weights deferred): nodeT[n][p*5+u] = sum_e sum_nnz v*scale*sh[o2+jj]*x[o1+u*d1+ii]
struct T2Tab { int ptr[21]; int xi[96]; int shi[96]; float c[96]; };
constexpr T2Tab build_t2(){
  T2Tab T{};
  const TPD& D = TPSel<2>::v;
  int ne = 0;
  for (int p = 0; p < D.np; ++p){
    const PathT& P = D.p[p];
    const W3NZ& W = w3_of(P.cid);
    int d1 = 2*P.l1+1;
    for (int u = 0; u < P.m1; ++u){
      T.ptr[p*5+u] = ne;
      for (int ni = 0; ni < W.n; ++ni){
        int ijk = W.ijk[ni]; int ii = ijk&7, jj = (ijk>>3)&7;
        T.xi[ne] = P.o1 + u*d1 + ii;
        T.shi[ne] = P.o2 + jj;
        T.c[ne] = W.v[ni]*P.scale;
        ++ne;
      }
    }
  }
  T.ptr[20] = ne;
  return T;
}

__device__ constexpr S2Tab<6144>  TAB0 = build_s2<0, 6144>();
__device__ constexpr S2Tab<49152> TAB1 = build_s2<1, 49152>();
__device__ constexpr T2Tab        TAB2 = build_t2();

// Compile-time for-loop (k_final)
template<int V> struct IC { static constexpr int value = V; };
template<int I, int N, class F>
__device__ __forceinline__ void sfor(F&& f){
  if constexpr (N - I == 1){ f(IC<I>{}); }
  else if constexpr (N - I > 1){
    constexpr int M = I + (N - I)/2;
    sfor<I, M>(f);
    sfor<M, N>(f);
  }
}

// ============================================================================
// Kernels
// ============================================================================

__device__ __forceinline__ void sh16(float x, float y, float z, float* b){
  const float s3 = 1.7320508075688772f, s5 = 2.2360679774997896f, s7 = 2.6457513110645907f;
  const float c30 = 0.9128709291752769f;   // sqrt(5/6)
  const float c32 = 0.6123724356957945f;   // sqrt(3/8)
  float y2 = y*y, x2z2 = x*x + z*z;
  float sh20 = s3*x*z, sh21 = s3*x*y, sh22 = y2 - 0.5f*x2z2, sh23 = s3*y*z, sh24 = 0.5f*s3*(z*z - x*x);
  float sh30 = c30*(sh20*z + sh24*x);
  float sh31 = s5*sh20*y;
  float sh32 = c32*(4.0f*y2 - x2z2)*x;
  float sh33 = 0.5f*y*(2.0f*y2 - 3.0f*x2z2);
  float sh34 = c32*z*(4.0f*y2 - x2z2);
  float sh35 = s5*sh24*y;
  float sh36 = c30*(sh24*z - sh20*x);
  b[0]=1.0f; b[1]=s3*x; b[2]=s3*y; b[3]=s3*z;
  b[4]=s5*sh20; b[5]=s5*sh21; b[6]=s5*sh22; b[7]=s5*sh23; b[8]=s5*sh24;
  b[9]=s7*sh30; b[10]=s7*sh31; b[11]=s7*sh32; b[12]=s7*sh33; b[13]=s7*sh34; b[14]=s7*sh35; b[15]=s7*sh36;
}

// --- CSR build --------------------------------------------------------------

__global__ void __launch_bounds__(256) k_hist(const int* __restrict__ dst,
    int* __restrict__ deg, int E){
  int e = blockIdx.x*256 + threadIdx.x;
  if (e < E) atomicAdd(&deg[dst[e]], 1);
}

__global__ void __launch_bounds__(256) k_scan(const int* __restrict__ deg,
    int* __restrict__ row_start, int* __restrict__ cursor, int N){
  __shared__ int part[256];
  int t = threadIdx.x;
  int M = N + 1;
  int CH = (M + 255) / 256;
  int base = t * CH;
  int s = 0;
  for (int k = 0; k < CH; ++k){
    int idx = base + k;
    if (idx < N) s += deg[idx];
  }
  part[t] = s;
  __syncthreads();
  if (t == 0){
    int run = 0;
    for (int i = 0; i < 256; ++i){ int v = part[i]; part[i] = run; run += v; }
  }
  __syncthreads();
  int run = part[t];
  for (int k = 0; k < CH; ++k){
    int idx = base + k;
    if (idx < M){
      row_start[idx] = run;
      cursor[idx] = run;
      if (idx < N) run += deg[idx];
    }
  }
}

__global__ void __launch_bounds__(256) k_fill(const int* __restrict__ src,
    const int* __restrict__ dst, const float* __restrict__ evec,
    int* __restrict__ cursor, int* __restrict__ csr_src, float* __restrict__ csr_sh, int E){
  int e = blockIdx.x*256 + threadIdx.x;
  if (e >= E) return;
  int d = dst[e];
  int pos = atomicAdd(&cursor[d], 1);
  csr_src[pos] = src[e];
  float b[16];
  sh16(evec[3*(size_t)e], evec[3*(size_t)e+1], evec[3*(size_t)e+2], b);
  float4* o = (float4*)(csr_sh + (size_t)pos*16);
  o[0] = make_float4(b[0],b[1],b[2],b[3]);
  o[1] = make_float4(b[4],b[5],b[6],b[7]);
  o[2] = make_float4(b[8],b[9],b[10],b[11]);
  o[3] = make_float4(b[12],b[13],b[14],b[15]);
}

__global__ void __launch_bounds__(256) k_nodeA(const float* __restrict__ csr_sh,
    const int* __restrict__ row_start, float* __restrict__ nodeA, int N){
  int gid = blockIdx.x*256 + threadIdx.x;
  if (gid >= N*16) return;
  int n = gid >> 4, d = gid & 15;
  int rs = row_start[n], re = row_start[n+1];
  float s = 0.f;
  for (int j = rs; j < re; ++j) s += csr_sh[(size_t)j*16 + d];
  nodeA[gid] = s;
}

// --- TP0: wave-per-node moment M0[16][16] + table map -> nodeB[160] ---------
__global__ void __launch_bounds__(256) k_tp0(const float* __restrict__ nodeA,
    const float* __restrict__ csr_sh, const int* __restrict__ csr_src,
    const int* __restrict__ row_start, const float* __restrict__ w,
    float* __restrict__ nodeB, int N)
{
  __shared__ float M0[4*256];
  int tx = (int)threadIdx.x, wq = tx>>6, lane = tx&63;
  int n = blockIdx.x*4 + wq;
  bool nv = n < N;
  int rs = nv ? row_start[n] : 0, re_ = nv ? row_start[n+1] : 0;
  int j16 = lane>>2, d4 = lane&3;
  float4 m0 = make_float4(0.f,0.f,0.f,0.f);
  #pragma unroll 2
  for (int j = rs; j < re_; ++j){
    int s = csr_src[j];
    float4 x4 = *(const float4*)(nodeA + (size_t)s*16 + d4*4);
    float sv = csr_sh[(size_t)j*16 + j16];
    m0.x += x4.x*sv; m0.y += x4.y*sv; m0.z += x4.z*sv; m0.w += x4.w*sv;
  }
  *(float4*)&M0[wq*256 + j16*16 + d4*4] = m0;
  __syncthreads();
  const float* __restrict__ Mw = &M0[wq*256];
  #pragma unroll
  for (int r = 0; r < 3; ++r){
    int c = r*64 + lane;
    if (c < 160 && nv){
      float acc = 0.f;
      int e1 = TAB0.ptr[c+1];
      for (int k = TAB0.ptr[c]; k < e1; ++k){
        S2E e = TAB0.e[k];
        acc += e.c * w[e.mw & 2047u] * Mw[e.mw >> 11];
      }
      nodeB[(size_t)n*160 + c] = acc;
    }
  }
}

// --- TP1: wave-per-node moment M[16][160] + table map -> nodeC[160] ---------
__device__ __forceinline__ void fma16(float4* m, float4 x4,
    float4 s0, float4 s1, float4 s2, float4 s3){
  m[0].x+=x4.x*s0.x; m[0].y+=x4.y*s0.x; m[0].z+=x4.z*s0.x; m[0].w+=x4.w*s0.x;
  m[1].x+=x4.x*s0.y; m[1].y+=x4.y*s0.y; m[1].z+=x4.z*s0.y; m[1].w+=x4.w*s0.y;
  m[2].x+=x4.x*s0.z; m[2].y+=x4.y*s0.z; m[2].z+=x4.z*s0.z; m[2].w+=x4.w*s0.z;
  m[3].x+=x4.x*s0.w; m[3].y+=x4.y*s0.w; m[3].z+=x4.z*s0.w; m[3].w+=x4.w*s0.w;
  m[4].x+=x4.x*s1.x; m[4].y+=x4.y*s1.x; m[4].z+=x4.z*s1.x; m[4].w+=x4.w*s1.x;
  m[5].x+=x4.x*s1.y; m[5].y+=x4.y*s1.y; m[5].z+=x4.z*s1.y; m[5].w+=x4.w*s1.y;
  m[6].x+=x4.x*s1.z; m[6].y+=x4.y*s1.z; m[6].z+=x4.z*s1.z; m[6].w+=x4.w*s1.z;
  m[7].x+=x4.x*s1.w; m[7].y+=x4.y*s1.w; m[7].z+=x4.z*s1.w; m[7].w+=x4.w*s1.w;
  m[8].x+=x4.x*s2.x; m[8].y+=x4.y*s2.x; m[8].z+=x4.z*s2.x; m[8].w+=x4.w*s2.x;
  m[9].x+=x4.x*s2.y; m[9].y+=x4.y*s2.y; m[9].z+=x4.z*s2.y; m[9].w+=x4.w*s2.y;
  m[10].x+=x4.x*s2.z; m[10].y+=x4.y*s2.z; m[10].z+=x4.z*s2.z; m[10].w+=x4.w*s2.z;
  m[11].x+=x4.x*s2.w; m[11].y+=x4.y*s2.w; m[11].z+=x4.z*s2.w; m[11].w+=x4.w*s2.w;
  m[12].x+=x4.x*s3.x; m[12].y+=x4.y*s3.x; m[12].z+=x4.z*s3.x; m[12].w+=x4.w*s3.x;
  m[13].x+=x4.x*s3.y; m[13].y+=x4.y*s3.y; m[13].z+=x4.z*s3.y; m[13].w+=x4.w*s3.y;
  m[14].x+=x4.x*s3.z; m[14].y+=x4.y*s3.z; m[14].z+=x4.z*s3.z; m[14].w+=x4.w*s3.z;
  m[15].x+=x4.x*s3.w; m[15].y+=x4.y*s3.w; m[15].z+=x4.z*s3.w; m[15].w+=x4.w*s3.w;
}

__global__ void __launch_bounds__(256) k_tp1(const float* __restrict__ nodeB,
    const float* __restrict__ csr_sh, const int* __restrict__ csr_src,
    const int* __restrict__ row_start, const float* __restrict__ w,
    float* __restrict__ nodeC, int N)
{
  __shared__ float M1[4*2560];
  int tx = (int)threadIdx.x, wq = tx>>6, lane = tx&63;
  int n = blockIdx.x*4 + wq;
  bool nv = n < N;
  int rs = nv ? row_start[n] : 0, re_ = nv ? row_start[n+1] : 0;
  bool ld = lane < 40;
  float4 m[16];
  #pragma unroll
  for (int i = 0; i < 16; ++i) m[i] = make_float4(0.f,0.f,0.f,0.f);
  const float4 z4 = make_float4(0.f,0.f,0.f,0.f);

  int j = rs;
  for (; j + 1 < re_; j += 2){
    int sA = csr_src[j], sB = csr_src[j+1];
    float4 xA = ld ? *(const float4*)(nodeB + (size_t)sA*160 + lane*4) : z4;
    float4 xB = ld ? *(const float4*)(nodeB + (size_t)sB*160 + lane*4) : z4;
    const float4* qA = (const float4*)(csr_sh + (size_t)j*16);
    const float4* qB = (const float4*)(csr_sh + (size_t)(j+1)*16);
    float4 a0=qA[0], a1=qA[1], a2=qA[2], a3=qA[3];
    float4 b0=qB[0], b1=qB[1], b2=qB[2], b3=qB[3];
    fma16(m, xA, a0,a1,a2,a3);
    fma16(m, xB, b0,b1,b2,b3);
  }
  if (j < re_){
    int sA = csr_src[j];
    float4 xA = ld ? *(const float4*)(nodeB + (size_t)sA*160 + lane*4) : z4;
    const float4* qA = (const float4*)(csr_sh + (size_t)j*16);
    fma16(m, xA, qA[0], qA[1], qA[2], qA[3]);
  }
  if (ld){
    #pragma unroll
    for (int jj = 0; jj < 16; ++jj)
      *(float4*)&M1[wq*2560 + jj*160 + lane*4] = m[jj];
  }
  __syncthreads();
  const float* __restrict__ Mw = &M1[wq*2560];
  #pragma unroll
  for (int r = 0; r < 3; ++r){
    int c = r*64 + lane;
    if (c < 160 && nv){
      float acc = 0.f;
      int e1 = TAB1.ptr[c+1];
      for (int k = TAB1.ptr[c]; k < e1; ++k){
        S2E e = TAB1.e[k];
        acc += e.c * w[e.mw & 2047u] * Mw[e.mw >> 11];
      }
      nodeC[(size_t)n*160 + c] = acc;
    }
  }
}

// --- TP2: wave-per-node, 3 edge-groups x 20 slot-lanes -> nodeT[20] ---------
__global__ void __launch_bounds__(256) k_tp2(const float* __restrict__ nodeC,
    const float* __restrict__ csr_sh, const int* __restrict__ csr_src,
    const int* __restrict__ row_start, float* __restrict__ nodeT, int N)
{
  int tx = (int)threadIdx.x, wq = tx>>6, lane = tx&63;
  int n = blockIdx.x*4 + wq;
  bool nv = n < N;
  int rs = nv ? row_start[n] : 0, re_ = nv ? row_start[n+1] : 0;
  int g = lane/20;              // 0..2 active, 3 = idle lanes 60..63
  int s = lane - g*20;
  bool act = lane < 60;
  int p0 = TAB2.ptr[s < 20 ? s : 0], p1 = TAB2.ptr[(s < 20 ? s : 0) + 1];
  float acc = 0.f;
  for (int base = rs; base < re_; base += 3){
    int jj = base + g;
    if (act && jj < re_){
      const float* __restrict__ xr = nodeC + (size_t)csr_src[jj]*160;
      const float* __restrict__ sr = csr_sh + (size_t)jj*16;
      for (int k = p0; k < p1; ++k)
        acc += TAB2.c[k] * xr[TAB2.xi[k]] * sr[TAB2.shi[k]];
    }
  }
  float t1 = __shfl_down(acc, 20);
  float t2 = __shfl_down(acc, 40);
  acc = acc + t1 + t2;
  if (lane < 20 && nv) nodeT[(size_t)n*20 + lane] = acc;
}

// --- final: per-graph sum of nodeT, then TP_OUT weight mixing ---------------
__device__ __forceinline__ int lbound(const int* __restrict__ a, int n, int key){
  int lo = 0, hi = n;
  while (lo < hi){ int m = (lo + hi) >> 1; if (a[m] < key) lo = m + 1; else hi = m; }
  return lo;
}

__global__ void __launch_bounds__(64) k_final(const float* __restrict__ nodeT,
    const int* __restrict__ batch, const float* __restrict__ w,
    float* __restrict__ out, int N){
  int g = blockIdx.x, f = threadIdx.x;
  int lo = lbound(batch, N, g), hi = lbound(batch, N, g + 1);
  __shared__ float gt[20];
  if (f < 20){
    float s = 0.f;
    for (int n = lo; n < hi; ++n) s += nodeT[(size_t)n*20 + f];
    gt[f] = s;
  }
  __syncthreads();
  float o = 0.f;
  sfor<0, 4>([&](auto PC){
    constexpr int pi = decltype(PC)::value;
    constexpr PathT P = TPSel<2>::v.p[pi];
    #pragma unroll
    for (int u = 0; u < 5; ++u) o += w[P.wof + u*64 + f] * gt[pi*5 + u];
  });
  out[(size_t)g*64 + f] = o * 2.5e-6f;   // 0.25 (4th segsum inv) / sqrt(100) / 1e4
}

// ============================================================================
extern "C" void kernel_launch(void* const* d_in, const int* in_sizes, int n_in,
                              void* d_out, int out_size, void* d_ws, size_t ws_size,
                              hipStream_t stream){
  const int*   eidx  = (const int*)d_in[0];
  const float* evec  = (const float*)d_in[1];
  const int*   batch = (const int*)d_in[2];
  const float* w_in  = (const float*)d_in[3];
  const float* w_ly  = (const float*)d_in[4];
  const float* w_out = (const float*)d_in[5];

  const int E = in_sizes[0]/2;   // 400000
  const int N = in_sizes[2];     // 25000
  const int G = out_size/64;     // 250
  const int* src = eidx;
  const int* dstp = eidx + E;

  const int NP = (N + 1 + 3) & ~3;
  int*   deg       = (int*)d_ws;             // [NP]
  int*   row_start = deg + NP;               // [NP]
  int*   cursor    = row_start + NP;         // [NP]
  int*   csr_src   = cursor + NP;            // [E]
  float* csr_sh    = (float*)(csr_src + E);  // [E,16]
  float* nodeA     = csr_sh + (size_t)E*16;  // [N,16]
  float* nodeB     = nodeA + (size_t)N*16;   // [N,160]
  float* nodeC     = nodeB + (size_t)N*160;  // [N,160]
  float* nodeT     = nodeC + (size_t)N*160;  // [N,20]

  hipMemsetAsync(deg, 0, (size_t)NP*sizeof(int), stream);

  int nbE = (E + 255)/256;
  k_hist<<<nbE, 256, 0, stream>>>(dstp, deg, E);
  k_scan<<<1, 256, 0, stream>>>(deg, row_start, cursor, N);
  k_fill<<<nbE, 256, 0, stream>>>(src, dstp, evec, cursor, csr_src, csr_sh, E);
  k_nodeA<<<(N*16 + 255)/256, 256, 0, stream>>>(csr_sh, row_start, nodeA, N);

  int nbN4 = (N + 3)/4;
  k_tp0<<<nbN4, 256, 0, stream>>>(nodeA, csr_sh, csr_src, row_start, w_in,  nodeB, N);
  k_tp1<<<nbN4, 256, 0, stream>>>(nodeB, csr_sh, csr_src, row_start, w_ly,  nodeC, N);
  k_tp2<<<nbN4, 256, 0, stream>>>(nodeC, csr_sh, csr_src, row_start, nodeT, N);

  k_final<<<G, 64, 0, stream>>>(nodeT, batch, w_out, (float*)d_out, N);
}